// Round 3
// baseline (145.560 us; speedup 1.0000x reference)
//
#include <hip/hip_runtime.h>
#include <hip/hip_bf16.h>

typedef __attribute__((ext_vector_type(4))) float f32x4;
typedef _Float16 f16;
typedef __attribute__((ext_vector_type(8))) f16 f16x8;
typedef __attribute__((ext_vector_type(4))) f16 f16x4;

#define LDQ 136   // 128 cols + 8 pad (16B) -> uniform LDS bank spread
#define LDV 72    // 64 cols + 8 pad

// Pack a row-major [K x Ntot] f32 weight into fp16 MFMA B-fragments:
// dst[((nt*4+kst)*64 + lane)*8 + e] = f16(w[32*kst + 8*(lane>>4) + e][16*nt + (lane&15)])
__global__ void pack_w_kernel(const float* __restrict__ w, f16* __restrict__ dst, int Ntot) {
  int idx = blockIdx.x * 256 + threadIdx.x;
  int total = (Ntot / 16) * 4 * 64;
  if (idx >= total) return;
  int lane = idx & 63;
  int kf = (idx >> 6) & 3;
  int nt = idx >> 8;
  int k0 = 32 * kf + 8 * (lane >> 4);
  int n = 16 * nt + (lane & 15);
  f16x8 v;
#pragma unroll
  for (int e = 0; e < 8; e++) v[e] = (f16)w[(k0 + e) * Ntot + n];
  *(f16x8*)(dst + (size_t)idx * 8) = v;
}

__global__ __launch_bounds__(256, 2) void winattn_main(
    const float* __restrict__ x, const float* __restrict__ mask,
    const float* __restrict__ bqkv, const float* __restrict__ bproj,
    const f16* __restrict__ wqkv_p, const f16* __restrict__ wproj_p,
    float* __restrict__ out) {
  __shared__ f16 Qs[64 * LDQ];
  __shared__ f16 Ks[64 * LDQ];
  __shared__ f16 Os[64 * LDQ];
  __shared__ f16 Vt[128 * LDV];

  const int tid = threadIdx.x;
  const int w = tid >> 6;    // wave id 0..3
  const int l = tid & 63;    // lane
  const int lg = l >> 4;     // lane group 0..3
  const int ll = l & 15;     // lane low
  const int b = blockIdx.x;  // window id

  const float* xw = x + (size_t)b * 49 * 128;

  // ---------------- stage 1: QKV = x @ Wqkv + b ----------------
  // A-fragments from global x (f32 -> f16): row = 16*mt+ll, k = 32*kst + 8*lg + e
  f16x8 af[4][4];
#pragma unroll
  for (int mt = 0; mt < 4; mt++) {
    int row = 16 * mt + ll;
#pragma unroll
    for (int kst = 0; kst < 4; kst++) {
      f16x8 a;
      if (row < 49) {
        const float* p = xw + row * 128 + kst * 32 + 8 * lg;
        f32x4 lo = *(const f32x4*)(p);
        f32x4 hi = *(const f32x4*)(p + 4);
#pragma unroll
        for (int e = 0; e < 4; e++) { a[e] = (f16)lo[e]; a[e + 4] = (f16)hi[e]; }
      } else {
#pragma unroll
        for (int e = 0; e < 8; e++) a[e] = (f16)0.f;
      }
      af[mt][kst] = a;
    }
  }
  // wave handles n-tiles nt = w, w+4, ..., w+20 (each weight frag read once per window)
  for (int nti = 0; nti < 6; nti++) {
    int nt = w + 4 * nti;
    f16x8 bfr[4];
#pragma unroll
    for (int kst = 0; kst < 4; kst++)
      bfr[kst] = *(const f16x8*)(wqkv_p + (size_t)(((nt * 4 + kst) * 64) + l) * 8);
    float bias = bqkv[16 * nt + ll];
    int c = 16 * nt + ll;  // global output col 0..383
#pragma unroll
    for (int mt = 0; mt < 4; mt++) {
      f32x4 acc = {0.f, 0.f, 0.f, 0.f};
#pragma unroll
      for (int kst = 0; kst < 4; kst++)
        acc = __builtin_amdgcn_mfma_f32_16x16x32_f16(af[mt][kst], bfr[kst], acc, 0, 0, 0);
      if (c < 128) {  // Q, row-major [token][col]
#pragma unroll
        for (int r = 0; r < 4; r++)
          Qs[(16 * mt + 4 * lg + r) * LDQ + c] = (f16)(acc[r] + bias);
      } else if (c < 256) {  // K
#pragma unroll
        for (int r = 0; r < 4; r++)
          Ks[(16 * mt + 4 * lg + r) * LDQ + (c - 128)] = (f16)(acc[r] + bias);
      } else {  // V stored transposed: Vt[d_global][token]
        f16x4 pk;
#pragma unroll
        for (int r = 0; r < 4; r++) pk[r] = (f16)(acc[r] + bias);
        *(f16x4*)(&Vt[(c - 256) * LDV + 16 * mt + 4 * lg]) = pk;
      }
    }
  }
  __syncthreads();

  // ---------------- stage 2: S = Q K^T (+mask), softmax ----------------
  const int h = w;  // one head per wave
  f32x4 s[4][4];    // [mt][nt] score tiles
  f16x8 kf[4];
#pragma unroll
  for (int nt = 0; nt < 4; nt++)
    kf[nt] = *(const f16x8*)(&Ks[(16 * nt + ll) * LDQ + 32 * h + 8 * lg]);
#pragma unroll
  for (int mt = 0; mt < 4; mt++) {
    f16x8 qf = *(const f16x8*)(&Qs[(16 * mt + ll) * LDQ + 32 * h + 8 * lg]);
#pragma unroll
    for (int nt = 0; nt < 4; nt++) {
      f32x4 z = {0.f, 0.f, 0.f, 0.f};
      s[mt][nt] = __builtin_amdgcn_mfma_f32_16x16x32_f16(qf, kf[nt], z, 0, 0, 0);
    }
  }
  // add window mask (additive, f32) and -inf for padded keys
  const float* mk = mask + (size_t)(b & 63) * 49 * 49;
#pragma unroll
  for (int mt = 0; mt < 4; mt++)
#pragma unroll
    for (int nt = 0; nt < 4; nt++)
#pragma unroll
      for (int r = 0; r < 4; r++) {
        int qr = 16 * mt + 4 * lg + r;
        int kc = 16 * nt + ll;
        float add;
        if (kc >= 49) add = -1e30f;
        else if (qr < 49) add = mk[qr * 49 + kc];
        else add = 0.f;
        s[mt][nt][r] += add;
      }
  // row softmax: row = 16*mt + 4*lg + r lives across the 16 lanes sharing lg (cols 16*nt+ll)
#pragma unroll
  for (int mt = 0; mt < 4; mt++) {
    float rmax[4], rsum[4];
#pragma unroll
    for (int r = 0; r < 4; r++) {
      float m = fmaxf(fmaxf(s[mt][0][r], s[mt][1][r]), fmaxf(s[mt][2][r], s[mt][3][r]));
#pragma unroll
      for (int xm = 1; xm < 16; xm <<= 1) m = fmaxf(m, __shfl_xor(m, xm, 64));
      rmax[r] = m;
    }
#pragma unroll
    for (int r = 0; r < 4; r++) {
      float sum = 0.f;
#pragma unroll
      for (int nt = 0; nt < 4; nt++) {
        float p = __expf(s[mt][nt][r] - rmax[r]);
        s[mt][nt][r] = p;
        sum += p;
      }
#pragma unroll
      for (int xm = 1; xm < 16; xm <<= 1) sum += __shfl_xor(sum, xm, 64);
      rsum[r] = sum;
    }
    // write P (f16) into the dead per-head Q/K LDS slices: keys 0-31 -> Qs, 32-63 -> Ks
#pragma unroll
    for (int r = 0; r < 4; r++) {
      float inv = 1.f / rsum[r];
#pragma unroll
      for (int nt = 0; nt < 4; nt++) {
        int q = 16 * mt + 4 * lg + r;
        int key = 16 * nt + ll;
        f16 pv = (f16)(s[mt][nt][r] * inv);
        if (key < 32) Qs[q * LDQ + 32 * h + key] = pv;
        else Ks[q * LDQ + 32 * h + (key - 32)] = pv;
      }
    }
  }
  __syncthreads();

  // ---------------- stage 3: O = P @ V ----------------
  f16x8 vf[2][2];  // [ntd][kst]: B[k=key][n=d] from Vt (16B contiguous)
#pragma unroll
  for (int ntd = 0; ntd < 2; ntd++)
#pragma unroll
    for (int kst = 0; kst < 2; kst++)
      vf[ntd][kst] = *(const f16x8*)(&Vt[(32 * h + 16 * ntd + ll) * LDV + 32 * kst + 8 * lg]);
#pragma unroll
  for (int mt = 0; mt < 4; mt++) {
    f16x8 a0 = *(const f16x8*)(&Qs[(16 * mt + ll) * LDQ + 32 * h + 8 * lg]);  // keys 0..31
    f16x8 a1 = *(const f16x8*)(&Ks[(16 * mt + ll) * LDQ + 32 * h + 8 * lg]);  // keys 32..63
#pragma unroll
    for (int ntd = 0; ntd < 2; ntd++) {
      f32x4 o = {0.f, 0.f, 0.f, 0.f};
      o = __builtin_amdgcn_mfma_f32_16x16x32_f16(a0, vf[ntd][0], o, 0, 0, 0);
      o = __builtin_amdgcn_mfma_f32_16x16x32_f16(a1, vf[ntd][1], o, 0, 0, 0);
#pragma unroll
      for (int r = 0; r < 4; r++)
        Os[(16 * mt + 4 * lg + r) * LDQ + 32 * h + 16 * ntd + ll] = (f16)o[r];
    }
  }
  __syncthreads();

  // ---------------- stage 4: out = O @ Wproj + b ----------------
  f16x8 of[4][4];
#pragma unroll
  for (int mt = 0; mt < 4; mt++)
#pragma unroll
    for (int kst = 0; kst < 4; kst++)
      of[mt][kst] = *(const f16x8*)(&Os[(16 * mt + ll) * LDQ + 32 * kst + 8 * lg]);
  for (int nti = 0; nti < 2; nti++) {
    int nt = w + 4 * nti;
    f16x8 bfr[4];
#pragma unroll
    for (int kst = 0; kst < 4; kst++)
      bfr[kst] = *(const f16x8*)(wproj_p + (size_t)(((nt * 4 + kst) * 64) + l) * 8);
    float bias = bproj[16 * nt + ll];
#pragma unroll
    for (int mt = 0; mt < 4; mt++) {
      f32x4 acc = {0.f, 0.f, 0.f, 0.f};
#pragma unroll
      for (int kst = 0; kst < 4; kst++)
        acc = __builtin_amdgcn_mfma_f32_16x16x32_f16(of[mt][kst], bfr[kst], acc, 0, 0, 0);
#pragma unroll
      for (int r = 0; r < 4; r++) {
        int row = 16 * mt + 4 * lg + r;
        if (row < 49)
          out[((size_t)b * 49 + row) * 128 + 16 * nt + ll] = acc[r] + bias;
      }
    }
  }
}

extern "C" void kernel_launch(void* const* d_in, const int* in_sizes, int n_in,
                              void* d_out, int out_size, void* d_ws, size_t ws_size,
                              hipStream_t stream) {
  const float* x = (const float*)d_in[0];
  const float* mask = (const float*)d_in[1];
  const float* wqkv = (const float*)d_in[2];
  const float* bqkv = (const float*)d_in[3];
  const float* wproj = (const float*)d_in[4];
  const float* bproj = (const float*)d_in[5];
  float* out = (float*)d_out;

  f16* wqkv_p = (f16*)d_ws;                   // 24*4*64*8 f16 = 96 KB
  f16* wproj_p = wqkv_p + 24 * 4 * 64 * 8;    // 8*4*64*8 f16 = 32 KB

  pack_w_kernel<<<24, 256, 0, stream>>>(wqkv, wqkv_p, 384);
  pack_w_kernel<<<8, 256, 0, stream>>>(wproj, wproj_p, 128);
  winattn_main<<<4096, 256, 0, stream>>>(x, mask, bqkv, bproj, wqkv_p, wproj_p, out);
}

// Round 4
// 124.743 us; speedup vs baseline: 1.1669x; 1.1669x over previous
//
#include <hip/hip_runtime.h>
#include <hip/hip_bf16.h>

typedef __attribute__((ext_vector_type(4))) float f32x4;
typedef _Float16 f16;
typedef __attribute__((ext_vector_type(8))) f16 f16x8;
typedef __attribute__((ext_vector_type(4))) f16 f16x4;

#define LDQ 136   // 128 cols + 8 pad (16B) -> keeps b128 alignment, spreads banks
#define LDV 72    // 64 cols + 8 pad

// Pack a row-major [K x Ntot] f32 weight into fp16 MFMA B-fragments:
// dst[((nt*4+kst)*64 + lane)*8 + e] = f16(w[32*kst + 8*(lane>>4) + e][16*nt + (lane&15)])
__global__ void pack_w_kernel(const float* __restrict__ w, f16* __restrict__ dst, int Ntot) {
  int idx = blockIdx.x * 256 + threadIdx.x;
  int total = (Ntot / 16) * 4 * 64;
  if (idx >= total) return;
  int lane = idx & 63;
  int kf = (idx >> 6) & 3;
  int nt = idx >> 8;
  int k0 = 32 * kf + 8 * (lane >> 4);
  int n = 16 * nt + (lane & 15);
  f16x8 v;
#pragma unroll
  for (int e = 0; e < 8; e++) v[e] = (f16)w[(k0 + e) * Ntot + n];
  *(f16x8*)(dst + (size_t)idx * 8) = v;
}

__global__ __launch_bounds__(256, 3) void winattn_main(
    const float* __restrict__ x, const float* __restrict__ mask,
    const float* __restrict__ bqkv, const float* __restrict__ bproj,
    const f16* __restrict__ wqkv_p, const f16* __restrict__ wproj_p,
    float* __restrict__ out) {
  // Qs doubles as Os (Q dead after stage 2; per-mt P-reads precede O-writes)
  __shared__ f16 Qs[64 * LDQ];
  __shared__ f16 Ks[64 * LDQ];
  __shared__ f16 Vt[128 * LDV];

  const int tid = threadIdx.x;
  const int h = tid >> 6;    // wave id == head id, 0..3
  const int l = tid & 63;    // lane
  const int lg = l >> 4;     // lane group 0..3
  const int ll = l & 15;     // lane low
  const int b = blockIdx.x;  // window id

  const float* xw = x + (size_t)b * 49 * 128;

  // ---------------- stage 1: QKV = x @ Wqkv + b (per-head tiles only) ----------------
  // A-fragments from global x (f32 -> f16): row = 16*mt+ll, k = 32*kst + 8*lg + e
  f16x8 af[4][4];
#pragma unroll
  for (int mt = 0; mt < 4; mt++) {
    int row = 16 * mt + ll;
#pragma unroll
    for (int kst = 0; kst < 4; kst++) {
      f16x8 a;
      if (row < 49) {
        const float* p = xw + row * 128 + kst * 32 + 8 * lg;
        f32x4 lo = *(const f32x4*)(p);
        f32x4 hi = *(const f32x4*)(p + 4);
#pragma unroll
        for (int e = 0; e < 4; e++) { a[e] = (f16)lo[e]; a[e + 4] = (f16)hi[e]; }
      } else {
#pragma unroll
        for (int e = 0; e < 8; e++) a[e] = (f16)0.f;
      }
      af[mt][kst] = a;
    }
  }
  // wave h computes exactly its own head's Q, K, V column-tiles -> no barrier needed
  // nt tiles: Q: 2h, 2h+1; K: 8+2h, 9+2h; V: 16+2h, 17+2h
  const int nts[6] = {2 * h, 2 * h + 1, 8 + 2 * h, 9 + 2 * h, 16 + 2 * h, 17 + 2 * h};
#pragma unroll
  for (int nti = 0; nti < 6; nti++) {
    int nt = nts[nti];
    f16x8 bfr[4];
#pragma unroll
    for (int kst = 0; kst < 4; kst++)
      bfr[kst] = *(const f16x8*)(wqkv_p + (size_t)(((nt * 4 + kst) * 64) + l) * 8);
    float bias = bqkv[16 * nt + ll];
    int c = 16 * nt + ll;  // global output col 0..383
#pragma unroll
    for (int mt = 0; mt < 4; mt++) {
      f32x4 acc = {0.f, 0.f, 0.f, 0.f};
#pragma unroll
      for (int kst = 0; kst < 4; kst++)
        acc = __builtin_amdgcn_mfma_f32_16x16x32_f16(af[mt][kst], bfr[kst], acc, 0, 0, 0);
      if (c < 128) {  // Q, row-major [token][col]
#pragma unroll
        for (int r = 0; r < 4; r++)
          Qs[(16 * mt + 4 * lg + r) * LDQ + c] = (f16)(acc[r] + bias);
      } else if (c < 256) {  // K
#pragma unroll
        for (int r = 0; r < 4; r++)
          Ks[(16 * mt + 4 * lg + r) * LDQ + (c - 128)] = (f16)(acc[r] + bias);
      } else {  // V stored transposed: Vt[d_global][token]
        f16x4 pk;
#pragma unroll
        for (int r = 0; r < 4; r++) pk[r] = (f16)(acc[r] + bias);
        *(f16x4*)(&Vt[(c - 256) * LDV + 16 * mt + 4 * lg]) = pk;
      }
    }
  }
  // no __syncthreads(): all LDS this wave reads below was written by this wave

  // ---------------- stage 2: S = Q K^T (+mask), softmax ----------------
  f32x4 s[4][4];    // [mt][nt] score tiles
  f16x8 kf[4];
#pragma unroll
  for (int nt = 0; nt < 4; nt++)
    kf[nt] = *(const f16x8*)(&Ks[(16 * nt + ll) * LDQ + 32 * h + 8 * lg]);
#pragma unroll
  for (int mt = 0; mt < 4; mt++) {
    f16x8 qf = *(const f16x8*)(&Qs[(16 * mt + ll) * LDQ + 32 * h + 8 * lg]);
#pragma unroll
    for (int nt = 0; nt < 4; nt++) {
      f32x4 z = {0.f, 0.f, 0.f, 0.f};
      s[mt][nt] = __builtin_amdgcn_mfma_f32_16x16x32_f16(qf, kf[nt], z, 0, 0, 0);
    }
  }
  // add window mask (additive, f32) and -inf for padded keys
  const float* mk = mask + (size_t)(b & 63) * 49 * 49;
#pragma unroll
  for (int mt = 0; mt < 4; mt++)
#pragma unroll
    for (int nt = 0; nt < 4; nt++)
#pragma unroll
      for (int r = 0; r < 4; r++) {
        int qr = 16 * mt + 4 * lg + r;
        int kc = 16 * nt + ll;
        float add;
        if (kc >= 49) add = -1e30f;
        else if (qr < 49) add = mk[qr * 49 + kc];
        else add = 0.f;
        s[mt][nt][r] += add;
      }
  // row softmax: row = 16*mt + 4*lg + r lives across the 16 lanes sharing lg
#pragma unroll
  for (int mt = 0; mt < 4; mt++) {
    float rmax[4], rsum[4];
#pragma unroll
    for (int r = 0; r < 4; r++) {
      float m = fmaxf(fmaxf(s[mt][0][r], s[mt][1][r]), fmaxf(s[mt][2][r], s[mt][3][r]));
#pragma unroll
      for (int xm = 1; xm < 16; xm <<= 1) m = fmaxf(m, __shfl_xor(m, xm, 64));
      rmax[r] = m;
    }
#pragma unroll
    for (int r = 0; r < 4; r++) {
      float sum = 0.f;
#pragma unroll
      for (int nt = 0; nt < 4; nt++) {
        float p = __expf(s[mt][nt][r] - rmax[r]);
        s[mt][nt][r] = p;
        sum += p;
      }
#pragma unroll
      for (int xm = 1; xm < 16; xm <<= 1) sum += __shfl_xor(sum, xm, 64);
      rsum[r] = sum;
    }
    // write P (f16) into the dead per-head Q/K LDS slices: keys 0-31 -> Qs, 32-63 -> Ks
#pragma unroll
    for (int r = 0; r < 4; r++) {
      float inv = 1.f / rsum[r];
#pragma unroll
      for (int nt = 0; nt < 4; nt++) {
        int q = 16 * mt + 4 * lg + r;
        int key = 16 * nt + ll;
        f16 pv = (f16)(s[mt][nt][r] * inv);
        if (key < 32) Qs[q * LDQ + 32 * h + key] = pv;
        else Ks[q * LDQ + 32 * h + (key - 32)] = pv;
      }
    }
  }
  // still no barrier: P/V for this head written by this wave

  // ---------------- stage 3: O = P @ V (O written back into Qs cols of this head) ----------------
  f16x8 vf[2][2];  // [ntd][kst]: B[k=key][n=d] from Vt (16B contiguous)
#pragma unroll
  for (int ntd = 0; ntd < 2; ntd++)
#pragma unroll
    for (int kst = 0; kst < 2; kst++)
      vf[ntd][kst] = *(const f16x8*)(&Vt[(32 * h + 16 * ntd + ll) * LDV + 32 * kst + 8 * lg]);
#pragma unroll
  for (int mt = 0; mt < 4; mt++) {
    f16x8 a0 = *(const f16x8*)(&Qs[(16 * mt + ll) * LDQ + 32 * h + 8 * lg]);  // keys 0..31
    f16x8 a1 = *(const f16x8*)(&Ks[(16 * mt + ll) * LDQ + 32 * h + 8 * lg]);  // keys 32..63
#pragma unroll
    for (int ntd = 0; ntd < 2; ntd++) {
      f32x4 o = {0.f, 0.f, 0.f, 0.f};
      o = __builtin_amdgcn_mfma_f32_16x16x32_f16(a0, vf[ntd][0], o, 0, 0, 0);
      o = __builtin_amdgcn_mfma_f32_16x16x32_f16(a1, vf[ntd][1], o, 0, 0, 0);
#pragma unroll
      for (int r = 0; r < 4; r++)
        Qs[(16 * mt + 4 * lg + r) * LDQ + 32 * h + 16 * ntd + ll] = (f16)o[r];
    }
  }
  __syncthreads();  // stage 4 mixes all heads' O columns

  // ---------------- stage 4: out = O @ Wproj + b (O read from Qs) ----------------
  f16x8 of[4][4];
#pragma unroll
  for (int mt = 0; mt < 4; mt++)
#pragma unroll
    for (int kst = 0; kst < 4; kst++)
      of[mt][kst] = *(const f16x8*)(&Qs[(16 * mt + ll) * LDQ + 32 * kst + 8 * lg]);
#pragma unroll
  for (int nti = 0; nti < 2; nti++) {
    int nt = h + 4 * nti;
    f16x8 bfr[4];
#pragma unroll
    for (int kst = 0; kst < 4; kst++)
      bfr[kst] = *(const f16x8*)(wproj_p + (size_t)(((nt * 4 + kst) * 64) + l) * 8);
    float bias = bproj[16 * nt + ll];
#pragma unroll
    for (int mt = 0; mt < 4; mt++) {
      f32x4 acc = {0.f, 0.f, 0.f, 0.f};
#pragma unroll
      for (int kst = 0; kst < 4; kst++)
        acc = __builtin_amdgcn_mfma_f32_16x16x32_f16(of[mt][kst], bfr[kst], acc, 0, 0, 0);
#pragma unroll
      for (int r = 0; r < 4; r++) {
        int row = 16 * mt + 4 * lg + r;
        if (row < 49)
          out[((size_t)b * 49 + row) * 128 + 16 * nt + ll] = acc[r] + bias;
      }
    }
  }
}

extern "C" void kernel_launch(void* const* d_in, const int* in_sizes, int n_in,
                              void* d_out, int out_size, void* d_ws, size_t ws_size,
                              hipStream_t stream) {
  const float* x = (const float*)d_in[0];
  const float* mask = (const float*)d_in[1];
  const float* wqkv = (const float*)d_in[2];
  const float* bqkv = (const float*)d_in[3];
  const float* wproj = (const float*)d_in[4];
  const float* bproj = (const float*)d_in[5];
  float* out = (float*)d_out;

  f16* wqkv_p = (f16*)d_ws;                   // 24*4*64*8 f16 = 96 KB
  f16* wproj_p = wqkv_p + 24 * 4 * 64 * 8;    // 8*4*64*8 f16 = 32 KB

  pack_w_kernel<<<24, 256, 0, stream>>>(wqkv, wqkv_p, 384);
  pack_w_kernel<<<8, 256, 0, stream>>>(wproj, wproj_p, 128);
  winattn_main<<<4096, 256, 0, stream>>>(x, mask, bqkv, bproj, wqkv_p, wproj_p, out);
}

// Round 6
// 121.206 us; speedup vs baseline: 1.2009x; 1.0292x over previous
//
#include <hip/hip_runtime.h>
#include <hip/hip_bf16.h>

typedef __attribute__((ext_vector_type(4))) float f32x4;
typedef _Float16 f16;
typedef __attribute__((ext_vector_type(8))) f16 f16x8;
typedef __attribute__((ext_vector_type(4))) f16 f16x4;
typedef __attribute__((ext_vector_type(2))) __fp16 fp16x2;

#define LDQ 136   // 128 cols + 8 pad (16B) -> keeps b128 alignment, spreads banks
#define LDV 72    // 64 cols + 8 pad

// Pack a row-major [K x Ntot] f32 weight into fp16 MFMA B-fragments:
// dst[((nt*4+kst)*64 + lane)*8 + e] = f16(w[32*kst + 8*(lane>>4) + e][16*nt + (lane&15)])
__global__ void pack_w_kernel(const float* __restrict__ w, f16* __restrict__ dst, int Ntot) {
  int idx = blockIdx.x * 256 + threadIdx.x;
  int total = (Ntot / 16) * 4 * 64;
  if (idx >= total) return;
  int lane = idx & 63;
  int kf = (idx >> 6) & 3;
  int nt = idx >> 8;
  int k0 = 32 * kf + 8 * (lane >> 4);
  int n = 16 * nt + (lane & 15);
  f16x8 v;
#pragma unroll
  for (int e = 0; e < 8; e++) v[e] = (f16)w[(k0 + e) * Ntot + n];
  *(f16x8*)(dst + (size_t)idx * 8) = v;
}

// Pre-pack mask into per-lane MFMA C-fragment layout, padding baked in:
// dst[((w*64 + l)*64) + mt*16 + nt*4 + r] =
//   kc>=49 ? -1e30 : (qr<49 ? mask[w][qr][kc] : 0),  qr=16mt+4(l>>4)+r, kc=16nt+(l&15)
__global__ void pack_mask_kernel(const float* __restrict__ mask, float* __restrict__ dst) {
  int idx = blockIdx.x * 256 + threadIdx.x;  // 64*64*64 = 262144
  int v = idx & 63;
  int l = (idx >> 6) & 63;
  int w = idx >> 12;
  int r = v & 3, nt = (v >> 2) & 3, mt = v >> 4;
  int qr = 16 * mt + 4 * (l >> 4) + r;
  int kc = 16 * nt + (l & 15);
  float val;
  if (kc >= 49) val = -1e30f;
  else if (qr < 49) val = mask[w * 2401 + qr * 49 + kc];
  else val = 0.f;
  dst[idx] = val;
}

__device__ __forceinline__ f16x8 cvt8(const float* p) {
  f32x4 lo = *(const f32x4*)(p);
  f32x4 hi = *(const f32x4*)(p + 4);
  union { f16x8 v; fp16x2 h[4]; } u;
  u.h[0] = __builtin_amdgcn_cvt_pkrtz(lo[0], lo[1]);
  u.h[1] = __builtin_amdgcn_cvt_pkrtz(lo[2], lo[3]);
  u.h[2] = __builtin_amdgcn_cvt_pkrtz(hi[0], hi[1]);
  u.h[3] = __builtin_amdgcn_cvt_pkrtz(hi[2], hi[3]);
  return u.v;
}

template <bool PM>
__global__ __launch_bounds__(256, 3) void winattn_main(
    const float* __restrict__ x, const float* __restrict__ mask,
    const float* __restrict__ mask_p,
    const float* __restrict__ bqkv, const float* __restrict__ bproj,
    const f16* __restrict__ wqkv_p, const f16* __restrict__ wproj_p,
    float* __restrict__ out) {
  // Qs doubles as P(lo) and O; Ks doubles as P(hi)
  __shared__ f16 Qs[64 * LDQ];
  __shared__ f16 Ks[64 * LDQ];
  __shared__ f16 Vt[128 * LDV];

  const int tid = threadIdx.x;
  const int h = tid >> 6;    // wave id == head id, 0..3
  const int l = tid & 63;    // lane
  const int lg = l >> 4;     // lane group 0..3
  const int ll = l & 15;     // lane low
  const int b = blockIdx.x;  // window id

  const float* xw = x + (size_t)b * 49 * 128;

  // ---------------- stage 1: QKV = x @ Wqkv + b (per-head tiles only) ----------------
  f16x8 af[4][4];
#pragma unroll
  for (int mt = 0; mt < 4; mt++) {
    int row = 16 * mt + ll;
#pragma unroll
    for (int kst = 0; kst < 4; kst++) {
      if (row < 49) {
        af[mt][kst] = cvt8(xw + row * 128 + kst * 32 + 8 * lg);
      } else {
        f16x8 a;
#pragma unroll
        for (int e = 0; e < 8; e++) a[e] = (f16)0.f;
        af[mt][kst] = a;
      }
    }
  }
  // Q tiles: nt = 2h, 2h+1  (cols 32h..32h+31, row-major into Qs)
#pragma unroll
  for (int qi = 0; qi < 2; qi++) {
    int nt = 2 * h + qi;
    f16x8 bfr[4];
#pragma unroll
    for (int kst = 0; kst < 4; kst++)
      bfr[kst] = *(const f16x8*)(wqkv_p + (size_t)(((nt * 4 + kst) * 64) + l) * 8);
    float bias = bqkv[16 * nt + ll];
    int c = 16 * nt + ll;
#pragma unroll
    for (int mt = 0; mt < 4; mt++) {
      f32x4 acc = {0.f, 0.f, 0.f, 0.f};
#pragma unroll
      for (int kst = 0; kst < 4; kst++)
        acc = __builtin_amdgcn_mfma_f32_16x16x32_f16(af[mt][kst], bfr[kst], acc, 0, 0, 0);
#pragma unroll
      for (int r = 0; r < 4; r++)
        Qs[(16 * mt + 4 * lg + r) * LDQ + c] = (f16)(acc[r] + bias);
    }
  }
  // K tiles: nt = 8+2h, 9+2h
#pragma unroll
  for (int ki = 0; ki < 2; ki++) {
    int nt = 8 + 2 * h + ki;
    f16x8 bfr[4];
#pragma unroll
    for (int kst = 0; kst < 4; kst++)
      bfr[kst] = *(const f16x8*)(wqkv_p + (size_t)(((nt * 4 + kst) * 64) + l) * 8);
    float bias = bqkv[16 * nt + ll];
    int c = 16 * (nt - 8) + ll;
#pragma unroll
    for (int mt = 0; mt < 4; mt++) {
      f32x4 acc = {0.f, 0.f, 0.f, 0.f};
#pragma unroll
      for (int kst = 0; kst < 4; kst++)
        acc = __builtin_amdgcn_mfma_f32_16x16x32_f16(af[mt][kst], bfr[kst], acc, 0, 0, 0);
#pragma unroll
      for (int r = 0; r < 4; r++)
        Ks[(16 * mt + 4 * lg + r) * LDQ + c] = (f16)(acc[r] + bias);
    }
  }
  // V tiles: nt = 16+2h, 17+2h (stored transposed Vt[d_global][token])
#pragma unroll
  for (int vi = 0; vi < 2; vi++) {
    int nt = 16 + 2 * h + vi;
    f16x8 bfr[4];
#pragma unroll
    for (int kst = 0; kst < 4; kst++)
      bfr[kst] = *(const f16x8*)(wqkv_p + (size_t)(((nt * 4 + kst) * 64) + l) * 8);
    float bias = bqkv[16 * nt + ll];
    int c = 16 * (nt - 16) + ll;  // d_global 0..127
#pragma unroll
    for (int mt = 0; mt < 4; mt++) {
      f32x4 acc = {0.f, 0.f, 0.f, 0.f};
#pragma unroll
      for (int kst = 0; kst < 4; kst++)
        acc = __builtin_amdgcn_mfma_f32_16x16x32_f16(af[mt][kst], bfr[kst], acc, 0, 0, 0);
      f16x4 pk;
#pragma unroll
      for (int r = 0; r < 4; r++) pk[r] = (f16)(acc[r] + bias);
      *(f16x4*)(&Vt[c * LDV + 16 * mt + 4 * lg]) = pk;
    }
  }
  // no __syncthreads(): all LDS this wave reads below was written by this wave

  // ---------------- stage 2: S = Q K^T (+mask), softmax (unnormalized P) ----------------
  float inv[4][4];  // 1/rowsum, [mt][r], consumed in stage 3
  f16x8 kf[4];
#pragma unroll
  for (int nt = 0; nt < 4; nt++)
    kf[nt] = *(const f16x8*)(&Ks[(16 * nt + ll) * LDQ + 32 * h + 8 * lg]);
  const f32x4* mp4 = PM ? (const f32x4*)(mask_p + (((size_t)(b & 63)) * 64 + l) * 64) : nullptr;
  const float* mk = mask + (size_t)(b & 63) * 49 * 49;
#pragma unroll
  for (int mt = 0; mt < 4; mt++) {
    // issue mask loads first so they overlap the MFMAs
    f32x4 mv[4];
    if (PM) {
#pragma unroll
      for (int nt = 0; nt < 4; nt++) mv[nt] = mp4[mt * 4 + nt];
    }
    f16x8 qf = *(const f16x8*)(&Qs[(16 * mt + ll) * LDQ + 32 * h + 8 * lg]);
    f32x4 s[4];
#pragma unroll
    for (int nt = 0; nt < 4; nt++) {
      f32x4 z = {0.f, 0.f, 0.f, 0.f};
      s[nt] = __builtin_amdgcn_mfma_f32_16x16x32_f16(qf, kf[nt], z, 0, 0, 0);
    }
    if (PM) {
#pragma unroll
      for (int nt = 0; nt < 4; nt++)
#pragma unroll
        for (int r = 0; r < 4; r++) s[nt][r] += mv[nt][r];
    } else {
#pragma unroll
      for (int nt = 0; nt < 4; nt++)
#pragma unroll
        for (int r = 0; r < 4; r++) {
          int qr = 16 * mt + 4 * lg + r;
          int kc = 16 * nt + ll;
          float add;
          if (kc >= 49) add = -1e30f;
          else if (qr < 49) add = mk[qr * 49 + kc];
          else add = 0.f;
          s[nt][r] += add;
        }
    }
    // row softmax: row's 64 cols live across the 16 lanes sharing lg (regs nt)
#pragma unroll
    for (int r = 0; r < 4; r++) {
      float m = fmaxf(fmaxf(s[0][r], s[1][r]), fmaxf(s[2][r], s[3][r]));
#pragma unroll
      for (int xm = 1; xm < 16; xm <<= 1) m = fmaxf(m, __shfl_xor(m, xm, 64));
      float sum = 0.f;
      f16 pv[4];
#pragma unroll
      for (int nt = 0; nt < 4; nt++) {
        float p = __expf(s[nt][r] - m);
        sum += p;
        pv[nt] = (f16)p;  // unnormalized P
      }
      // write P immediately (doesn't wait for the sum reduction)
      int q = 16 * mt + 4 * lg + r;
      Qs[q * LDQ + 32 * h + ll] = pv[0];
      Qs[q * LDQ + 32 * h + 16 + ll] = pv[1];
      Ks[q * LDQ + 32 * h + ll] = pv[2];
      Ks[q * LDQ + 32 * h + 16 + ll] = pv[3];
#pragma unroll
      for (int xm = 1; xm < 16; xm <<= 1) sum += __shfl_xor(sum, xm, 64);
      inv[mt][r] = __builtin_amdgcn_rcpf(sum);
    }
  }
  // still no barrier: P/V for this head written by this wave

  // ---------------- stage 3: O = P @ V, scaled by inv (O back into Qs) ----------------
  f16x8 vf[2][2];  // [ntd][kst]: B[k=key][n=d] from Vt (16B contiguous)
#pragma unroll
  for (int ntd = 0; ntd < 2; ntd++)
#pragma unroll
    for (int kst = 0; kst < 2; kst++)
      vf[ntd][kst] = *(const f16x8*)(&Vt[(32 * h + 16 * ntd + ll) * LDV + 32 * kst + 8 * lg]);
#pragma unroll
  for (int mt = 0; mt < 4; mt++) {
    f16x8 a0 = *(const f16x8*)(&Qs[(16 * mt + ll) * LDQ + 32 * h + 8 * lg]);  // keys 0..31
    f16x8 a1 = *(const f16x8*)(&Ks[(16 * mt + ll) * LDQ + 32 * h + 8 * lg]);  // keys 32..63
#pragma unroll
    for (int ntd = 0; ntd < 2; ntd++) {
      f32x4 o = {0.f, 0.f, 0.f, 0.f};
      o = __builtin_amdgcn_mfma_f32_16x16x32_f16(a0, vf[ntd][0], o, 0, 0, 0);
      o = __builtin_amdgcn_mfma_f32_16x16x32_f16(a1, vf[ntd][1], o, 0, 0, 0);
#pragma unroll
      for (int r = 0; r < 4; r++)
        Qs[(16 * mt + 4 * lg + r) * LDQ + 32 * h + 16 * ntd + ll] = (f16)(o[r] * inv[mt][r]);
    }
  }

  // hoist stage-4 weight fragments above the barrier (VMEM hides under sync)
  f16x8 bfr2[2][4];
  float bias2[2];
#pragma unroll
  for (int nti = 0; nti < 2; nti++) {
    int nt = h + 4 * nti;
#pragma unroll
    for (int kst = 0; kst < 4; kst++)
      bfr2[nti][kst] = *(const f16x8*)(wproj_p + (size_t)(((nt * 4 + kst) * 64) + l) * 8);
    bias2[nti] = bproj[16 * nt + ll];
  }
  __syncthreads();  // stage 4 mixes all heads' O columns

  // ---------------- stage 4: out = O @ Wproj + b (O read from Qs) ----------------
  f16x8 of[4][4];
#pragma unroll
  for (int mt = 0; mt < 4; mt++)
#pragma unroll
    for (int kst = 0; kst < 4; kst++)
      of[mt][kst] = *(const f16x8*)(&Qs[(16 * mt + ll) * LDQ + 32 * kst + 8 * lg]);
#pragma unroll
  for (int nti = 0; nti < 2; nti++) {
    int nt = h + 4 * nti;
#pragma unroll
    for (int mt = 0; mt < 4; mt++) {
      f32x4 acc = {0.f, 0.f, 0.f, 0.f};
#pragma unroll
      for (int kst = 0; kst < 4; kst++)
        acc = __builtin_amdgcn_mfma_f32_16x16x32_f16(of[mt][kst], bfr2[nti][kst], acc, 0, 0, 0);
#pragma unroll
      for (int r = 0; r < 4; r++) {
        int row = 16 * mt + 4 * lg + r;
        if (row < 49)
          out[((size_t)b * 49 + row) * 128 + 16 * nt + ll] = acc[r] + bias2[nti];
      }
    }
  }
}

extern "C" void kernel_launch(void* const* d_in, const int* in_sizes, int n_in,
                              void* d_out, int out_size, void* d_ws, size_t ws_size,
                              hipStream_t stream) {
  const float* x = (const float*)d_in[0];
  const float* mask = (const float*)d_in[1];
  const float* wqkv = (const float*)d_in[2];
  const float* bqkv = (const float*)d_in[3];
  const float* wproj = (const float*)d_in[4];
  const float* bproj = (const float*)d_in[5];
  float* out = (float*)d_out;

  f16* wqkv_p = (f16*)d_ws;                   // 24*4*64*8 f16 = 96 KB
  f16* wproj_p = wqkv_p + 24 * 4 * 64 * 8;    // 8*4*64*8 f16 = 32 KB
  float* mask_p = (float*)((char*)d_ws + 128 * 1024);  // 64*64*64 f32 = 1 MB

  const size_t need = 128 * 1024 + 64 * 64 * 64 * sizeof(float);
  const bool pm = ws_size >= need;

  pack_w_kernel<<<24, 256, 0, stream>>>(wqkv, wqkv_p, 384);
  pack_w_kernel<<<8, 256, 0, stream>>>(wproj, wproj_p, 128);
  if (pm) {
    pack_mask_kernel<<<1024, 256, 0, stream>>>(mask, mask_p);
    winattn_main<true><<<4096, 256, 0, stream>>>(x, mask, mask_p, bqkv, bproj, wqkv_p, wproj_p, out);
  } else {
    winattn_main<false><<<4096, 256, 0, stream>>>(x, mask, nullptr, bqkv, bproj, wqkv_p, wproj_p, out);
  }
}